// Round 4
// baseline (130.529 us; speedup 1.0000x reference)
//
#include <hip/hip_runtime.h>

#define NROW 4096
#define CH   256
#define MAXNNZ 128

typedef short  short8  __attribute__((ext_vector_type(8)));
typedef unsigned short ushort8 __attribute__((ext_vector_type(8)));
typedef float  f32x4   __attribute__((ext_vector_type(4)));

__device__ inline unsigned short f2bf(float f) {
  unsigned u = __float_as_uint(f);
  return (unsigned short)((u + 0x7fffu + ((u >> 16) & 1u)) >> 16);
}
__device__ inline float bf2f(unsigned short h) {
  return __uint_as_float((unsigned)h << 16);
}
// popc(m & lanes_below_me) + base, 2 VALU ops
__device__ inline int mbcnt64(unsigned long long m, int base) {
  int t = __builtin_amdgcn_mbcnt_lo((unsigned)m, (unsigned)base);
  return __builtin_amdgcn_mbcnt_hi((unsigned)(m >> 32), t);
}

// ---------------------------------------------------------------------------
// Build 3 CSRs (Ld, Lup, P) from dense L. One wave per row.
// All 16 float4 loads hoisted (pinned by sched_barrier); compaction goes to
// LDS (lgkmcnt path — keeps scattered stores OFF vmcnt so loads stay in
// flight); one coalesced global write-out per row at the end.
__global__ __launch_bounds__(256) void build_csr3(
    const float* __restrict__ L0, const float* __restrict__ L1,
    const float* __restrict__ L2, int* __restrict__ idx,
    float* __restrict__ val, int* __restrict__ cnt) {
  __shared__ int   sj[4][MAXNNZ];
  __shared__ float sv[4][MAXNNZ];
  const float* L = (blockIdx.y == 0) ? L0 : (blockIdx.y == 1) ? L1 : L2;
  int wi   = threadIdx.x >> 6;
  int row  = blockIdx.x * 4 + wi;
  int lane = threadIdx.x & 63;
  const float4* Lrow = (const float4*)(L + (size_t)row * NROW);

  float4 v[16];
#pragma unroll
  for (int k = 0; k < 16; ++k) v[k] = Lrow[k * 64 + lane];
  __builtin_amdgcn_sched_barrier(0);   // keep all 16 loads issued up front

  int base = 0;
#pragma unroll
  for (int k = 0; k < 16; ++k) {
    float4 q = v[k];
    bool n0 = q.x != 0.f, n1 = q.y != 0.f, n2 = q.z != 0.f, n3 = q.w != 0.f;
    unsigned long long b0 = __ballot(n0), b1 = __ballot(n1);
    unsigned long long b2 = __ballot(n2), b3 = __ballot(n3);
    int off = mbcnt64(b3, mbcnt64(b2, mbcnt64(b1, mbcnt64(b0, base))));
    int col0 = k * 256 + lane * 4;
    if (n0) { if (off < MAXNNZ) { sj[wi][off] = col0;     sv[wi][off] = q.x; } ++off; }
    if (n1) { if (off < MAXNNZ) { sj[wi][off] = col0 + 1; sv[wi][off] = q.y; } ++off; }
    if (n2) { if (off < MAXNNZ) { sj[wi][off] = col0 + 2; sv[wi][off] = q.z; } ++off; }
    if (n3) { if (off < MAXNNZ) { sj[wi][off] = col0 + 3; sv[wi][off] = q.w; } ++off; }
    base += __popcll(b0) + __popcll(b1) + __popcll(b2) + __popcll(b3);
  }

  // coalesced write-out: 128 idx + 128 val per row, 8B per lane each
  size_t rbase = ((size_t)blockIdx.y * NROW + row) * MAXNNZ;
  int2   ji = ((const int2*)sj[wi])[lane];
  float2 vf = ((const float2*)sv[wi])[lane];
  ((int2*)(idx + rbase))[lane] = ji;
  ((float2*)(val + rbase))[lane] = vf;
  if (lane == 0) cnt[blockIdx.y * NROW + row] = base < MAXNNZ ? base : MAXNNZ;
}

// ---------------------------------------------------------------------------
// Fold attention vector into linear weights (q = branch*2 + (0:src,1:dst)).
__global__ void fold_att(const float* __restrict__ Wi, const float* __restrict__ bi,
                         const float* __restrict__ ai,
                         const float* __restrict__ Ws, const float* __restrict__ bs,
                         const float* __restrict__ as_,
                         float* __restrict__ wfold, float* __restrict__ bfold) {
  int b  = blockIdx.x >> 1;
  int sd = blockIdx.x & 1;
  const float* Ww  = b ? Ws : Wi;
  const float* Wb  = b ? bs : bi;
  const float* att = (b ? as_ : ai) + sd * 512;
  int c = threadIdx.x;
  float acc = 0.f;
  for (int k = 0; k < 512; ++k) acc += att[k] * Ww[k * 256 + c];
  wfold[blockIdx.x * 256 + c] = acc;
  __shared__ float sb[256];
  sb[c] = att[c] * Wb[c] + att[c + 256] * Wb[c + 256];
  __syncthreads();
  for (int s2 = 128; s2 > 0; s2 >>= 1) { if (c < s2) sb[c] += sb[c + s2]; __syncthreads(); }
  if (c == 0) bfold[blockIdx.x] = sb[0];
}

// ---------------------------------------------------------------------------
// sdv[q][n] = x[n,:] . wfold[q] + bfold[q]
__global__ void src_dst(const float* __restrict__ x, const float* __restrict__ wfold,
                        const float* __restrict__ bfold, float* __restrict__ sdv) {
  int q    = blockIdx.y;
  int row  = blockIdx.x * 4 + (threadIdx.x >> 6);
  int lane = threadIdx.x & 63;
  const float4* xr = (const float4*)(x + (size_t)row * CH);
  const float4* wr = (const float4*)(wfold + q * CH);
  float4 a = xr[lane];
  float4 b = wr[lane];
  float s = a.x * b.x + a.y * b.y + a.z * b.z + a.w * b.w;
  for (int o = 32; o; o >>= 1) s += __shfl_xor(s, o);
  if (lane == 0) sdv[q * NROW + row] = s + bfold[q];
}

// ---------------------------------------------------------------------------
// One dispatch converting x, Wirr_w, Wsol_w, Whar_w to bf16 (4 f32/thread).
__global__ void cvt_all(const float* __restrict__ x, const float* __restrict__ Wi,
                        const float* __restrict__ Ws, const float* __restrict__ Wh,
                        unsigned short* __restrict__ xbf, unsigned short* __restrict__ Bbf) {
  int i = blockIdx.x * 256 + threadIdx.x;       // float4 index
  const float* src; unsigned short* dst; int o;
  if (i < 262144)        { src = x;  dst = xbf;          o = i; }
  else if (i < 294912)   { src = Wi; dst = Bbf;          o = i - 262144; }
  else if (i < 327680)   { src = Ws; dst = Bbf + 131072; o = i - 294912; }
  else                   { src = Wh; dst = Bbf + 262144; o = i - 327680; }
  float4 v = ((const float4*)src)[o];
  ushort4 u;
  u.x = f2bf(v.x); u.y = f2bf(v.y); u.z = f2bf(v.z); u.w = f2bf(v.w);
  ((ushort4*)dst)[o] = u;
}

// ---------------------------------------------------------------------------
// Y[4096][1280] (bf16) = A[4096][256](bf16) @ Bt[1280][256](bf16)^T
// 64x64 tile, 4 waves, full-K (=256) staged in LDS with XOR swizzle.
__global__ __launch_bounds__(256, 2) void gemm_mfma(const unsigned short* __restrict__ A,
                                                    const unsigned short* __restrict__ Bt,
                                                    unsigned short* __restrict__ Y) {
  __shared__ unsigned short sA[64 * 256];
  __shared__ unsigned short sB[64 * 256];
  const int m0 = blockIdx.x * 64, n0 = blockIdx.y * 64;
  const int tid = threadIdx.x, wid = tid >> 6, lane = tid & 63;

  for (int c = 0; c < 8; ++c) {
    int chunk = c * 256 + tid;
    int r  = chunk >> 5;
    int cb = (chunk & 31) * 16;
    int cbs = cb ^ ((r & 7) << 4);
    ushort8 va = *(const ushort8*)((const char*)(A  + (size_t)(m0 + r) * 256) + cb);
    *(ushort8*)((char*)sA + r * 512 + cbs) = va;
    ushort8 vb = *(const ushort8*)((const char*)(Bt + (size_t)(n0 + r) * 256) + cb);
    *(ushort8*)((char*)sB + r * 512 + cbs) = vb;
  }
  __syncthreads();

  const int wr = wid >> 1, wc = wid & 1;
  const int lr = lane & 15, kg = lane >> 4;
  f32x4 acc[2][2] = {};
#pragma unroll
  for (int ks = 0; ks < 8; ++ks) {
    int kb = ks * 64 + kg * 16;
    short8 a0, a1, b0, b1;
    { int r = wr * 32 + lr;      a0 = *(const short8*)((const char*)sA + r * 512 + (kb ^ ((r & 7) << 4))); }
    { int r = wr * 32 + 16 + lr; a1 = *(const short8*)((const char*)sA + r * 512 + (kb ^ ((r & 7) << 4))); }
    { int r = wc * 32 + lr;      b0 = *(const short8*)((const char*)sB + r * 512 + (kb ^ ((r & 7) << 4))); }
    { int r = wc * 32 + 16 + lr; b1 = *(const short8*)((const char*)sB + r * 512 + (kb ^ ((r & 7) << 4))); }
    acc[0][0] = __builtin_amdgcn_mfma_f32_16x16x32_bf16(a0, b0, acc[0][0], 0, 0, 0);
    acc[0][1] = __builtin_amdgcn_mfma_f32_16x16x32_bf16(a0, b1, acc[0][1], 0, 0, 0);
    acc[1][0] = __builtin_amdgcn_mfma_f32_16x16x32_bf16(a1, b0, acc[1][0], 0, 0, 0);
    acc[1][1] = __builtin_amdgcn_mfma_f32_16x16x32_bf16(a1, b1, acc[1][1], 0, 0, 0);
  }

#pragma unroll
  for (int mi = 0; mi < 2; ++mi)
#pragma unroll
    for (int ni = 0; ni < 2; ++ni) {
      int col = n0 + wc * 32 + ni * 16 + lr;
#pragma unroll
      for (int r4 = 0; r4 < 4; ++r4) {
        int row = m0 + wr * 32 + mi * 16 + kg * 4 + r4;
        Y[(size_t)row * 1280 + col] = f2bf(acc[mi][ni][r4]);
      }
    }
}

// ---------------------------------------------------------------------------
// U = Y0 + L @ Y1 (in place into the Y0 column range).
__global__ void spmm_add(const int* __restrict__ idx, const float* __restrict__ val,
                         const int* __restrict__ cnt, unsigned short* __restrict__ Y) {
  int br = blockIdx.y;
  int row = blockIdx.x, t = threadIdx.x;
  size_t rbase = ((size_t)br * NROW + row) * MAXNNZ;
  int n = cnt[br * NROW + row];
  __shared__ int   sj[MAXNNZ];
  __shared__ float sv[MAXNNZ];
  if (t < n) { sj[t] = idx[rbase + t]; sv[t] = val[rbase + t]; }
  __syncthreads();
  int cs = br ? 768 : 256, cd = br ? 512 : 0;
  float acc = bf2f(Y[(size_t)row * 1280 + cd + t]);
  for (int k = 0; k < n; ++k) acc += sv[k] * bf2f(Y[(size_t)sj[k] * 1280 + cs + t]);
  Y[(size_t)row * 1280 + cd + t] = f2bf(acc);
}

// ---------------------------------------------------------------------------
// Z[row] = alpha_d @ U_d + alpha_s @ U_s + P @ Yh + (all biases)
__global__ void final_z(const int* __restrict__ idx, const float* __restrict__ val,
                        const int* __restrict__ cnt, const float* __restrict__ sdv,
                        const unsigned short* __restrict__ Y,
                        const float* __restrict__ bi, const float* __restrict__ bs,
                        const float* __restrict__ bh, float* __restrict__ Z) {
  int row = blockIdx.x, t = threadIdx.x;
  __shared__ float sa[MAXNNZ];
  __shared__ int   sj[MAXNNZ];
  __shared__ float red[4];
  float acc = bi[t] + bi[256 + t] + bs[t] + bs[256 + t] + bh[t];

  for (int br = 0; br < 2; ++br) {
    size_t rbase = ((size_t)br * NROW + row) * MAXNNZ;
    int n = cnt[br * NROW + row];
    const float* srcv = sdv + (2 * br) * NROW;
    const float* dstv = sdv + (2 * br + 1) * NROW;
    float e = -1e30f;
    if (t < n) {
      int j = idx[rbase + t];
      sj[t] = j;
      float v = srcv[row] + dstv[j];
      e = v >= 0.f ? v : 0.01f * v;
    }
    float m = e;
    for (int o = 32; o; o >>= 1) m = fmaxf(m, __shfl_xor(m, o));
    if ((t & 63) == 0) red[t >> 6] = m;
    __syncthreads();
    m = fmaxf(fmaxf(red[0], red[1]), fmaxf(red[2], red[3]));
    __syncthreads();
    float p = (t < n) ? expf(e - m) : 0.f;
    float s = p;
    for (int o = 32; o; o >>= 1) s += __shfl_xor(s, o);
    if ((t & 63) == 0) red[t >> 6] = s;
    __syncthreads();
    s = red[0] + red[1] + red[2] + red[3];
    if (t < n) sa[t] = p / s;
    __syncthreads();
    int cd = br ? 512 : 0;
    for (int k = 0; k < n; ++k)
      acc += sa[k] * bf2f(Y[(size_t)sj[k] * 1280 + cd + t]);
    __syncthreads();
  }

  {
    size_t rbase = ((size_t)2 * NROW + row) * MAXNNZ;
    int n = cnt[2 * NROW + row];
    if (t < n) { sj[t] = idx[rbase + t]; sa[t] = val[rbase + t]; }
    __syncthreads();
    for (int k = 0; k < n; ++k)
      acc += sa[k] * bf2f(Y[(size_t)sj[k] * 1280 + 1024 + t]);
  }
  Z[(size_t)row * 256 + t] = acc;
}

// ---------------------------------------------------------------------------
extern "C" void kernel_launch(void* const* d_in, const int* in_sizes, int n_in,
                              void* d_out, int out_size, void* d_ws, size_t ws_size,
                              hipStream_t stream) {
  const float* x      = (const float*)d_in[0];
  const float* Lup    = (const float*)d_in[1];
  const float* Ld     = (const float*)d_in[2];
  const float* P      = (const float*)d_in[3];
  const float* Wirr_w = (const float*)d_in[4];
  const float* Wirr_b = (const float*)d_in[5];
  const float* Wsol_w = (const float*)d_in[6];
  const float* Wsol_b = (const float*)d_in[7];
  const float* Whar_w = (const float*)d_in[8];
  const float* Whar_b = (const float*)d_in[9];
  const float* att_i  = (const float*)d_in[10];
  const float* att_s  = (const float*)d_in[11];
  float* Z = (float*)d_out;

  char* w = (char*)d_ws;
  auto alloc = [&](size_t bytes) { void* p = (void*)w; w += (bytes + 255) & ~(size_t)255; return p; };

  int*   idx  = (int*)alloc((size_t)3 * NROW * MAXNNZ * 4);
  float* val  = (float*)alloc((size_t)3 * NROW * MAXNNZ * 4);
  int*   cnt  = (int*)alloc((size_t)3 * NROW * 4);
  float* wfold = (float*)alloc(4 * CH * 4);
  float* bfold = (float*)alloc(4 * 4);
  float* sdv   = (float*)alloc(4 * NROW * 4);
  unsigned short* xbf = (unsigned short*)alloc((size_t)NROW * CH * 2);
  unsigned short* Bbf = (unsigned short*)alloc((size_t)1280 * CH * 2);
  unsigned short* Y   = (unsigned short*)alloc((size_t)NROW * 1280 * 2);

  // CSR slot order: 0 = Ld (irr), 1 = Lup (sol), 2 = P
  build_csr3<<<dim3(NROW / 4, 3), 256, 0, stream>>>(Ld, Lup, P, idx, val, cnt);

  fold_att<<<4, 256, 0, stream>>>(Wirr_w, Wirr_b, att_i, Wsol_w, Wsol_b, att_s, wfold, bfold);
  src_dst<<<dim3(NROW / 4, 4), 256, 0, stream>>>(x, wfold, bfold, sdv);

  cvt_all<<<(262144 + 32768 + 32768 + 16384) / 256, 256, 0, stream>>>(x, Wirr_w, Wsol_w, Whar_w, xbf, Bbf);

  gemm_mfma<<<dim3(NROW / 64, 1280 / 64), 256, 0, stream>>>(xbf, Bbf, Y);

  spmm_add<<<dim3(NROW, 2), 256, 0, stream>>>(idx, val, cnt, Y);

  final_z<<<NROW, 256, 0, stream>>>(idx, val, cnt, sdv, Y, Wirr_b, Wsol_b, Whar_b, Z);
}

// Round 5
// 127.196 us; speedup vs baseline: 1.0262x; 1.0262x over previous
//
#include <hip/hip_runtime.h>

#define NROW 4096
#define CH   256
#define MAXNNZ 128

typedef short  short8  __attribute__((ext_vector_type(8)));
typedef unsigned short ushort8 __attribute__((ext_vector_type(8)));
typedef float  f32x4   __attribute__((ext_vector_type(4)));

__device__ inline unsigned short f2bf(float f) {
  unsigned u = __float_as_uint(f);
  return (unsigned short)((u + 0x7fffu + ((u >> 16) & 1u)) >> 16);
}
__device__ inline float bf2f(unsigned short h) {
  return __uint_as_float((unsigned)h << 16);
}
// popc(m & lanes_below_me) + base, 2 VALU ops
__device__ inline int mbcnt64(unsigned long long m, int base) {
  int t = __builtin_amdgcn_mbcnt_lo((unsigned)m, (unsigned)base);
  return __builtin_amdgcn_mbcnt_hi((unsigned)(m >> 32), t);
}

// ---------------------------------------------------------------------------
// Build 3 CSRs (Ld, Lup, P). ONE BLOCK PER (matrix,row); each of the 4 waves
// owns a 1024-col segment: 4 independent float4 loads/thread (hoistable in
// 16 VGPRs), 4-iter ballot-compaction into a per-wave LDS slice, then a
// 4-entry prefix + coalesced write-out. Output bitwise == column-sorted CSR.
__global__ __launch_bounds__(256) void build_csr3(
    const float* __restrict__ L0, const float* __restrict__ L1,
    const float* __restrict__ L2, int* __restrict__ idx,
    float* __restrict__ val, int* __restrict__ cnt) {
  __shared__ int   sj[4][MAXNNZ];
  __shared__ float sv[4][MAXNNZ];
  __shared__ int   scnt[4];
  const int mat = blockIdx.y;
  const int row = blockIdx.x;
  const float* L = (mat == 0) ? L0 : (mat == 1) ? L1 : L2;
  const int wi = threadIdx.x >> 6, lane = threadIdx.x & 63;
  // wave wi covers cols [wi*1024, wi*1024+1024)
  const float4* Lseg = (const float4*)(L + (size_t)row * NROW) + wi * 256;

  float4 v0 = Lseg[lane], v1 = Lseg[64 + lane], v2 = Lseg[128 + lane], v3 = Lseg[192 + lane];

  int base = 0;
  float4 vv[4] = {v0, v1, v2, v3};
#pragma unroll
  for (int k = 0; k < 4; ++k) {
    float4 q = vv[k];
    bool n0 = q.x != 0.f, n1 = q.y != 0.f, n2 = q.z != 0.f, n3 = q.w != 0.f;
    unsigned long long b0 = __ballot(n0), b1 = __ballot(n1);
    unsigned long long b2 = __ballot(n2), b3 = __ballot(n3);
    int off = mbcnt64(b3, mbcnt64(b2, mbcnt64(b1, mbcnt64(b0, base))));
    int col0 = wi * 1024 + k * 256 + lane * 4;
    if (n0) { if (off < MAXNNZ) { sj[wi][off] = col0;     sv[wi][off] = q.x; } ++off; }
    if (n1) { if (off < MAXNNZ) { sj[wi][off] = col0 + 1; sv[wi][off] = q.y; } ++off; }
    if (n2) { if (off < MAXNNZ) { sj[wi][off] = col0 + 2; sv[wi][off] = q.z; } ++off; }
    if (n3) { if (off < MAXNNZ) { sj[wi][off] = col0 + 3; sv[wi][off] = q.w; } ++off; }
    base += __popcll(b0) + __popcll(b1) + __popcll(b2) + __popcll(b3);
  }
  if (lane == 0) scnt[wi] = base < MAXNNZ ? base : MAXNNZ;
  __syncthreads();

  int c0 = scnt[0], c1 = scnt[1], c2 = scnt[2], c3 = scnt[3];
  int total = c0 + c1 + c2 + c3;
  if (total > MAXNNZ) total = MAXNNZ;
  size_t rbase = ((size_t)mat * NROW + row) * MAXNNZ;
  int t = threadIdx.x;
  if (t < total) {
    int s, o;
    if      (t < c0)           { s = 0; o = t; }
    else if (t < c0 + c1)      { s = 1; o = t - c0; }
    else if (t < c0 + c1 + c2) { s = 2; o = t - c0 - c1; }
    else                       { s = 3; o = t - c0 - c1 - c2; }
    idx[rbase + t] = sj[s][o];
    val[rbase + t] = sv[s][o];
  }
  if (t == 0) cnt[mat * NROW + row] = total;
}

// ---------------------------------------------------------------------------
// Fold attention vector into linear weights (q = branch*2 + (0:src,1:dst)).
__global__ void fold_att(const float* __restrict__ Wi, const float* __restrict__ bi,
                         const float* __restrict__ ai,
                         const float* __restrict__ Ws, const float* __restrict__ bs,
                         const float* __restrict__ as_,
                         float* __restrict__ wfold, float* __restrict__ bfold) {
  int b  = blockIdx.x >> 1;
  int sd = blockIdx.x & 1;
  const float* Ww  = b ? Ws : Wi;
  const float* Wb  = b ? bs : bi;
  const float* att = (b ? as_ : ai) + sd * 512;
  int c = threadIdx.x;
  float acc = 0.f;
  for (int k = 0; k < 512; ++k) acc += att[k] * Ww[k * 256 + c];
  wfold[blockIdx.x * 256 + c] = acc;
  __shared__ float sb[256];
  sb[c] = att[c] * Wb[c] + att[c + 256] * Wb[c + 256];
  __syncthreads();
  for (int s2 = 128; s2 > 0; s2 >>= 1) { if (c < s2) sb[c] += sb[c + s2]; __syncthreads(); }
  if (c == 0) bfold[blockIdx.x] = sb[0];
}

// ---------------------------------------------------------------------------
// sdv[q][n] = x[n,:] . wfold[q] + bfold[q]
__global__ void src_dst(const float* __restrict__ x, const float* __restrict__ wfold,
                        const float* __restrict__ bfold, float* __restrict__ sdv) {
  int q    = blockIdx.y;
  int row  = blockIdx.x * 4 + (threadIdx.x >> 6);
  int lane = threadIdx.x & 63;
  const float4* xr = (const float4*)(x + (size_t)row * CH);
  const float4* wr = (const float4*)(wfold + q * CH);
  float4 a = xr[lane];
  float4 b = wr[lane];
  float s = a.x * b.x + a.y * b.y + a.z * b.z + a.w * b.w;
  for (int o = 32; o; o >>= 1) s += __shfl_xor(s, o);
  if (lane == 0) sdv[q * NROW + row] = s + bfold[q];
}

// ---------------------------------------------------------------------------
// One dispatch converting x, Wirr_w, Wsol_w, Whar_w to bf16 (4 f32/thread).
__global__ void cvt_all(const float* __restrict__ x, const float* __restrict__ Wi,
                        const float* __restrict__ Ws, const float* __restrict__ Wh,
                        unsigned short* __restrict__ xbf, unsigned short* __restrict__ Bbf) {
  int i = blockIdx.x * 256 + threadIdx.x;       // float4 index
  const float* src; unsigned short* dst; int o;
  if (i < 262144)        { src = x;  dst = xbf;          o = i; }
  else if (i < 294912)   { src = Wi; dst = Bbf;          o = i - 262144; }
  else if (i < 327680)   { src = Ws; dst = Bbf + 131072; o = i - 294912; }
  else                   { src = Wh; dst = Bbf + 262144; o = i - 327680; }
  float4 v = ((const float4*)src)[o];
  ushort4 u;
  u.x = f2bf(v.x); u.y = f2bf(v.y); u.z = f2bf(v.z); u.w = f2bf(v.w);
  ((ushort4*)dst)[o] = u;
}

// ---------------------------------------------------------------------------
// Y[4096][1280] (bf16) = A[4096][256](bf16) @ Bt[1280][256](bf16)^T
// 64x64 tile, 4 waves, full-K (=256) staged in LDS with XOR swizzle.
__global__ __launch_bounds__(256, 2) void gemm_mfma(const unsigned short* __restrict__ A,
                                                    const unsigned short* __restrict__ Bt,
                                                    unsigned short* __restrict__ Y) {
  __shared__ unsigned short sA[64 * 256];
  __shared__ unsigned short sB[64 * 256];
  const int m0 = blockIdx.x * 64, n0 = blockIdx.y * 64;
  const int tid = threadIdx.x, wid = tid >> 6, lane = tid & 63;

  for (int c = 0; c < 8; ++c) {
    int chunk = c * 256 + tid;
    int r  = chunk >> 5;
    int cb = (chunk & 31) * 16;
    int cbs = cb ^ ((r & 7) << 4);
    ushort8 va = *(const ushort8*)((const char*)(A  + (size_t)(m0 + r) * 256) + cb);
    *(ushort8*)((char*)sA + r * 512 + cbs) = va;
    ushort8 vb = *(const ushort8*)((const char*)(Bt + (size_t)(n0 + r) * 256) + cb);
    *(ushort8*)((char*)sB + r * 512 + cbs) = vb;
  }
  __syncthreads();

  const int wr = wid >> 1, wc = wid & 1;
  const int lr = lane & 15, kg = lane >> 4;
  f32x4 acc[2][2] = {};
#pragma unroll
  for (int ks = 0; ks < 8; ++ks) {
    int kb = ks * 64 + kg * 16;
    short8 a0, a1, b0, b1;
    { int r = wr * 32 + lr;      a0 = *(const short8*)((const char*)sA + r * 512 + (kb ^ ((r & 7) << 4))); }
    { int r = wr * 32 + 16 + lr; a1 = *(const short8*)((const char*)sA + r * 512 + (kb ^ ((r & 7) << 4))); }
    { int r = wc * 32 + lr;      b0 = *(const short8*)((const char*)sB + r * 512 + (kb ^ ((r & 7) << 4))); }
    { int r = wc * 32 + 16 + lr; b1 = *(const short8*)((const char*)sB + r * 512 + (kb ^ ((r & 7) << 4))); }
    acc[0][0] = __builtin_amdgcn_mfma_f32_16x16x32_bf16(a0, b0, acc[0][0], 0, 0, 0);
    acc[0][1] = __builtin_amdgcn_mfma_f32_16x16x32_bf16(a0, b1, acc[0][1], 0, 0, 0);
    acc[1][0] = __builtin_amdgcn_mfma_f32_16x16x32_bf16(a1, b0, acc[1][0], 0, 0, 0);
    acc[1][1] = __builtin_amdgcn_mfma_f32_16x16x32_bf16(a1, b1, acc[1][1], 0, 0, 0);
  }

#pragma unroll
  for (int mi = 0; mi < 2; ++mi)
#pragma unroll
    for (int ni = 0; ni < 2; ++ni) {
      int col = n0 + wc * 32 + ni * 16 + lr;
#pragma unroll
      for (int r4 = 0; r4 < 4; ++r4) {
        int row = m0 + wr * 32 + mi * 16 + kg * 4 + r4;
        Y[(size_t)row * 1280 + col] = f2bf(acc[mi][ni][r4]);
      }
    }
}

// ---------------------------------------------------------------------------
// U = Y0 + L @ Y1 (in place into the Y0 column range).
__global__ void spmm_add(const int* __restrict__ idx, const float* __restrict__ val,
                         const int* __restrict__ cnt, unsigned short* __restrict__ Y) {
  int br = blockIdx.y;
  int row = blockIdx.x, t = threadIdx.x;
  size_t rbase = ((size_t)br * NROW + row) * MAXNNZ;
  int n = cnt[br * NROW + row];
  __shared__ int   sj[MAXNNZ];
  __shared__ float sv[MAXNNZ];
  if (t < n) { sj[t] = idx[rbase + t]; sv[t] = val[rbase + t]; }
  __syncthreads();
  int cs = br ? 768 : 256, cd = br ? 512 : 0;
  float acc = bf2f(Y[(size_t)row * 1280 + cd + t]);
  for (int k = 0; k < n; ++k) acc += sv[k] * bf2f(Y[(size_t)sj[k] * 1280 + cs + t]);
  Y[(size_t)row * 1280 + cd + t] = f2bf(acc);
}

// ---------------------------------------------------------------------------
// Z[row] = alpha_d @ U_d + alpha_s @ U_s + P @ Yh + (all biases)
__global__ void final_z(const int* __restrict__ idx, const float* __restrict__ val,
                        const int* __restrict__ cnt, const float* __restrict__ sdv,
                        const unsigned short* __restrict__ Y,
                        const float* __restrict__ bi, const float* __restrict__ bs,
                        const float* __restrict__ bh, float* __restrict__ Z) {
  int row = blockIdx.x, t = threadIdx.x;
  __shared__ float sa[MAXNNZ];
  __shared__ int   sj[MAXNNZ];
  __shared__ float red[4];
  float acc = bi[t] + bi[256 + t] + bs[t] + bs[256 + t] + bh[t];

  for (int br = 0; br < 2; ++br) {
    size_t rbase = ((size_t)br * NROW + row) * MAXNNZ;
    int n = cnt[br * NROW + row];
    const float* srcv = sdv + (2 * br) * NROW;
    const float* dstv = sdv + (2 * br + 1) * NROW;
    float e = -1e30f;
    if (t < n) {
      int j = idx[rbase + t];
      sj[t] = j;
      float v = srcv[row] + dstv[j];
      e = v >= 0.f ? v : 0.01f * v;
    }
    float m = e;
    for (int o = 32; o; o >>= 1) m = fmaxf(m, __shfl_xor(m, o));
    if ((t & 63) == 0) red[t >> 6] = m;
    __syncthreads();
    m = fmaxf(fmaxf(red[0], red[1]), fmaxf(red[2], red[3]));
    __syncthreads();
    float p = (t < n) ? expf(e - m) : 0.f;
    float s = p;
    for (int o = 32; o; o >>= 1) s += __shfl_xor(s, o);
    if ((t & 63) == 0) red[t >> 6] = s;
    __syncthreads();
    s = red[0] + red[1] + red[2] + red[3];
    if (t < n) sa[t] = p / s;
    __syncthreads();
    int cd = br ? 512 : 0;
    for (int k = 0; k < n; ++k)
      acc += sa[k] * bf2f(Y[(size_t)sj[k] * 1280 + cd + t]);
    __syncthreads();
  }

  {
    size_t rbase = ((size_t)2 * NROW + row) * MAXNNZ;
    int n = cnt[2 * NROW + row];
    if (t < n) { sj[t] = idx[rbase + t]; sa[t] = val[rbase + t]; }
    __syncthreads();
    for (int k = 0; k < n; ++k)
      acc += sa[k] * bf2f(Y[(size_t)sj[k] * 1280 + 1024 + t]);
  }
  Z[(size_t)row * 256 + t] = acc;
}

// ---------------------------------------------------------------------------
extern "C" void kernel_launch(void* const* d_in, const int* in_sizes, int n_in,
                              void* d_out, int out_size, void* d_ws, size_t ws_size,
                              hipStream_t stream) {
  const float* x      = (const float*)d_in[0];
  const float* Lup    = (const float*)d_in[1];
  const float* Ld     = (const float*)d_in[2];
  const float* P      = (const float*)d_in[3];
  const float* Wirr_w = (const float*)d_in[4];
  const float* Wirr_b = (const float*)d_in[5];
  const float* Wsol_w = (const float*)d_in[6];
  const float* Wsol_b = (const float*)d_in[7];
  const float* Whar_w = (const float*)d_in[8];
  const float* Whar_b = (const float*)d_in[9];
  const float* att_i  = (const float*)d_in[10];
  const float* att_s  = (const float*)d_in[11];
  float* Z = (float*)d_out;

  char* w = (char*)d_ws;
  auto alloc = [&](size_t bytes) { void* p = (void*)w; w += (bytes + 255) & ~(size_t)255; return p; };

  int*   idx  = (int*)alloc((size_t)3 * NROW * MAXNNZ * 4);
  float* val  = (float*)alloc((size_t)3 * NROW * MAXNNZ * 4);
  int*   cnt  = (int*)alloc((size_t)3 * NROW * 4);
  float* wfold = (float*)alloc(4 * CH * 4);
  float* bfold = (float*)alloc(4 * 4);
  float* sdv   = (float*)alloc(4 * NROW * 4);
  unsigned short* xbf = (unsigned short*)alloc((size_t)NROW * CH * 2);
  unsigned short* Bbf = (unsigned short*)alloc((size_t)1280 * CH * 2);
  unsigned short* Y   = (unsigned short*)alloc((size_t)NROW * 1280 * 2);

  // CSR slot order: 0 = Ld (irr), 1 = Lup (sol), 2 = P
  build_csr3<<<dim3(NROW, 3), 256, 0, stream>>>(Ld, Lup, P, idx, val, cnt);

  fold_att<<<4, 256, 0, stream>>>(Wirr_w, Wirr_b, att_i, Wsol_w, Wsol_b, att_s, wfold, bfold);
  src_dst<<<dim3(NROW / 4, 4), 256, 0, stream>>>(x, wfold, bfold, sdv);

  cvt_all<<<(262144 + 32768 + 32768 + 16384) / 256, 256, 0, stream>>>(x, Wirr_w, Wsol_w, Whar_w, xbf, Bbf);

  gemm_mfma<<<dim3(NROW / 64, 1280 / 64), 256, 0, stream>>>(xbf, Bbf, Y);

  spmm_add<<<dim3(NROW, 2), 256, 0, stream>>>(idx, val, cnt, Y);

  final_z<<<NROW, 256, 0, stream>>>(idx, val, cnt, sdv, Y, Wirr_b, Wsol_b, Whar_b, Z);
}